// Round 1
// 15307.178 us; speedup vs baseline: 1.2256x; 1.2256x over previous
//
#include <hip/hip_runtime.h>
#include <stdint.h>

#define NU 4096
#define NB 2048
#define KK2 8192
#define ITERS 100
#define CAP 262144
#define THETA 0.05f
#define KC 512              // host fixup k-panel (verified)

// ws layout (bytes) — unchanged
#define OFF_BT   0u
#define OFF_A0   67108864u
#define OFF_A1   83886080u
#define OFF_SUS  100663296u
#define OFF_CNT  102760448u
#define REQ_WS   102761472u

// GEMM geometry: BM=256 x BN=128 x BK=64, 512 thr (8 waves 4Mx2N), grid 8x32=256
#define NTILES 128           // K = 8192 / 64
#define BUFB   49152         // bytes per LDS buffer: (256+128)*64*2
#define A1OFF  16384
#define BOFF   32768

typedef float f32x4 __attribute__((ext_vector_type(4)));
typedef __bf16 bf16x8 __attribute__((ext_vector_type(8)));

__device__ __forceinline__ unsigned short f2bf(float x) {
  unsigned u = __float_as_uint(x);
  u += 0x7FFFu + ((u >> 16) & 1u);
  return (unsigned short)(u >> 16);
}
__device__ __forceinline__ float bf2f(unsigned short h) {
  return __uint_as_float(((unsigned)h) << 16);
}

__device__ __forceinline__ void gl16(const unsigned short* g, char* l) {
  __builtin_amdgcn_global_load_lds(
      (const __attribute__((address_space(1))) unsigned int*)g,
      (__attribute__((address_space(3))) unsigned int*)l, 16, 0, 0);
}

__global__ void fill_kernel(float* __restrict__ out, float v) {
  int t = blockIdx.x * blockDim.x + threadIdx.x;
  int base = t << 3;
  float4 a = make_float4(v, v, v, v);
  *(float4*)(out + base) = a;
  *(float4*)(out + base + 4) = a;
}

__global__ void decompose_kernel(const float* __restrict__ W,
                                 unsigned short* __restrict__ Bt) {
  int t = blockIdx.x * blockDim.x + threadIdx.x;
  int base = t << 2;
  int j = base >> 12;
  int k = base & 4095;
  float4 w = *(const float4*)(W + (size_t)j * NU + k);
  unsigned short h0 = f2bf(w.x), h1 = f2bf(w.y), h2 = f2bf(w.z), h3 = f2bf(w.w);
  ushort4 hi = make_ushort4(h0, h1, h2, h3);
  ushort4 lo = make_ushort4(f2bf(w.x - bf2f(h0)), f2bf(w.y - bf2f(h1)),
                            f2bf(w.z - bf2f(h2)), f2bf(w.w - bf2f(h3)));
  *(ushort4*)(Bt + (size_t)j * KK2 + k) = hi;
  *(ushort4*)(Bt + (size_t)j * KK2 + NU + k) = lo;
}

// Initial state: P (fp32 +-1, exact) -> A0 bf16 +-1.
__global__ void init_kernel(const float* __restrict__ P,
                            unsigned short* __restrict__ A0) {
  int t = blockIdx.x * blockDim.x + threadIdx.x;
  int base = t << 3;
  float4 a = *(const float4*)(P + base);
  float4 b = *(const float4*)(P + base + 4);
  float hv[8] = {a.x, a.y, a.z, a.w, b.x, b.y, b.z, b.w};
  uint4 pk;
  unsigned short s[8];
#pragma unroll
  for (int i = 0; i < 8; ++i)
    s[i] = (hv[i] >= 0.0f) ? (unsigned short)0x3F80u : (unsigned short)0xBF80u;
  pk.x = (unsigned)s[0] | ((unsigned)s[1] << 16);
  pk.y = (unsigned)s[2] | ((unsigned)s[3] << 16);
  pk.z = (unsigned)s[4] | ((unsigned)s[5] << 16);
  pk.w = (unsigned)s[6] | ((unsigned)s[7] << 16);
  *(uint4*)(A0 + base) = pk;
}

// Counted-vmcnt deep-pipelined GEMM (T2+T3+T4+T5 structure):
//  - 3 LDS buffers (144 KiB), global_load_lds width=16, prefetch 2 K-tiles deep
//  - one raw s_barrier + one s_waitcnt vmcnt(6) per K-tile (never 0 mid-loop)
//  - XOR slot-swizzle (slot ^= row&7) applied on the GLOBAL source address
//    (LDS dest stays linear, rule 21) and identically on the ds_read side:
//    8 lanes per 4-bank group per b128 read = conflict-free optimum.
//  - Ledger: at tile-k boundary, outstanding = tile k+1 (6 oldest loads) +
//    tile k+2 (6 newest). vmcnt(6) retires exactly tile k+1. Buffers rotate
//    mod 3, so staging of k+2 never touches the buffer being read (k) or the
//    one read next (k+1). Tail: k=126/127 use vmcnt(0) (once, tail only).
// MFMA core & C/D mapping unchanged (certified m89/m91).
__global__ void __launch_bounds__(512, 2)
gemm_fused_kernel(const unsigned short* __restrict__ A,
                  const unsigned short* __restrict__ Bt,
                  unsigned short* __restrict__ Anext,
                  float* __restrict__ outF, int writeOut,
                  int* __restrict__ counter,
                  int* __restrict__ suspects) {
  __shared__ __align__(16) unsigned short sL[3 * 24576];   // 147456 B
  const int tid = threadIdx.x;
  const int wave = tid >> 6, lane = tid & 63;
  const int lm = lane & 15, lk = lane >> 4;
  const int wm = wave >> 1, wn = wave & 1;           // 4M x 2N wave grid
  const int nt = blockIdx.x & 31, mt = blockIdx.x >> 5;
  const int mBase = mt << 8, nBase = nt << 7;

  // ---- staging lane constants (chunk = 128 rows x 64 cols = 16 KB) ----
  // wave w stages chunk rows [w*16, w*16+16); load l covers 8 rows.
  // LDS linear byte o = w*2048 + l*1024 + lane*16 -> row r = o>>7, phys slot
  // = lane&7. Global fetch uses logical slot = phys ^ (r&7)  (involution).
  const int rl0 = (wave << 4) + (lane >> 3);
  const int swz = (((lane & 7) ^ ((lane >> 3) & 7)) << 3);  // elems
  const unsigned short* pA00 = A + (size_t)(mBase + rl0) * NU + swz;
  const unsigned short* pA01 = A + (size_t)(mBase + rl0 + 8) * NU + swz;
  const unsigned short* pA10 = A + (size_t)(mBase + 128 + rl0) * NU + swz;
  const unsigned short* pA11 = A + (size_t)(mBase + 128 + rl0 + 8) * NU + swz;
  const unsigned short* pB0 = Bt + (size_t)(nBase + rl0) * KK2 + swz;
  const unsigned short* pB1 = Bt + (size_t)(nBase + rl0 + 8) * KK2 + swz;
  const int ldsW = wave << 11;                       // wave * 2048 B
  char* sBase = (char*)sL;

  auto STAGE = [&](int kt, int soff) {
    const int kA = (kt << 6) & (NU - 1);             // A wraps K=4096
    const int kB = kt << 6;
    char* lb = sBase + soff;
    gl16(pA00 + kA, lb + ldsW);
    gl16(pA01 + kA, lb + ldsW + 1024);
    gl16(pA10 + kA, lb + A1OFF + ldsW);
    gl16(pA11 + kA, lb + A1OFF + ldsW + 1024);
    gl16(pB0 + kB, lb + BOFF + ldsW);
    gl16(pB1 + kB, lb + BOFF + ldsW + 1024);
  };

  // ---- fragment-read lane constants ----
  // logical (row r, slot sl=kks*4+lk), r&7 == lm&7 -> phys byte term:
  // kks=0: t0 = ((lk^(lm&7))<<4); kks=1: t0 ^ 64.
  const int t0 = ((lk ^ (lm & 7)) << 4);
  const int aB = (((wm << 6) + lm) << 7);            // (wm*64+lm)*128
  const int bB = BOFF + (((wn << 6) + lm) << 7);

  f32x4 acc[4][4] = {};

  STAGE(0, 0);
  STAGE(1, BUFB);
  asm volatile("s_waitcnt vmcnt(6)" ::: "memory");   // tile 0 landed
  __builtin_amdgcn_s_barrier();
  __builtin_amdgcn_sched_barrier(0);

  int bo = 0, so = 2 * BUFB;
  for (int k = 0; k < NTILES; ++k) {
    if (k < NTILES - 2) STAGE(k + 2, so);            // issue-early (T14)
    const char* bufc = sBase + bo;
#pragma unroll
    for (int kks = 0; kks < 2; ++kks) {
      const int t = t0 ^ (kks << 6);
      bf16x8 af[4], bfr[4];
#pragma unroll
      for (int i = 0; i < 4; ++i)
        af[i] = *(const bf16x8*)(bufc + aB + i * 2048 + t);
#pragma unroll
      for (int j = 0; j < 4; ++j)
        bfr[j] = *(const bf16x8*)(bufc + bB + j * 2048 + t);
      __builtin_amdgcn_s_setprio(1);
#pragma unroll
      for (int i = 0; i < 4; ++i)
#pragma unroll
        for (int j = 0; j < 4; ++j)
          acc[i][j] = __builtin_amdgcn_mfma_f32_16x16x32_bf16(
              af[i], bfr[j], acc[i][j], 0, 0, 0);
      __builtin_amdgcn_s_setprio(0);
    }
    __builtin_amdgcn_sched_barrier(0);
    if (k < NTILES - 2)
      asm volatile("s_waitcnt vmcnt(6)" ::: "memory");  // tile k+1 landed
    else
      asm volatile("s_waitcnt vmcnt(0)" ::: "memory");  // tail drain
    __builtin_amdgcn_s_barrier();
    __builtin_amdgcn_sched_barrier(0);
    bo += BUFB; if (bo == 3 * BUFB) bo = 0;
    so += BUFB; if (so == 3 * BUFB) so = 0;
  }

  // Fused sign epilogue. C/D layout (m89/m91): col=lane&15, row=(lane>>4)*4+reg
#pragma unroll
  for (int i = 0; i < 4; ++i)
#pragma unroll
    for (int j = 0; j < 4; ++j)
#pragma unroll
      for (int r = 0; r < 4; ++r) {
        const int row = mBase + (wm << 6) + i * 16 + (lk << 2) + r;
        const int col = nBase + (wn << 6) + j * 16 + lm;
        const float h = acc[i][j][r];
        Anext[(size_t)row * NU + col] =
            (h >= 0.0f) ? (unsigned short)0x3F80u : (unsigned short)0xBF80u;
        if (fabsf(h) < THETA) {
          int idx = atomicAdd(counter, 1);
          if (idx < CAP) suspects[idx] = (row << 12) | col;
        }
        if (writeOut)
          outF[(size_t)row * NU + col] = (h >= 0.0f) ? 1.0f : -1.0f;
      }
}

// Suspects, 8 lanes per suspect (one per KC=512 panel). Same sequential fp32
// chain as the round-8-verified version; bitwise-identical sign decision.
__global__ void fixup_kernel(const unsigned short* __restrict__ Acur,
                             const float* __restrict__ W,
                             unsigned short* __restrict__ Anext,
                             float* __restrict__ outF, int writeOut,
                             const int* __restrict__ counter,
                             const int* __restrict__ suspects,
                             int* __restrict__ flagOv) {
  int n = *counter;
  if (blockIdx.x == 0 && threadIdx.x == 0 && n > CAP) atomicAdd(flagOv, 1);
  n = n < CAP ? n : CAP;
  const int lane = threadIdx.x & 7;                       // panel index
  const int gid = (blockIdx.x * blockDim.x + threadIdx.x) >> 3;
  const int ngrp = (gridDim.x * blockDim.x) >> 3;
  for (int i = gid; i < n; i += ngrp) {
    int idx = suspects[i];
    int b = idx >> 12, j = idx & 4095;
    const float* wrow = W + (size_t)j * NU + lane * KC;
    const unsigned short* arow = Acur + (size_t)b * NU + lane * KC;
    float part = 0.0f;
    for (int k = 0; k < KC; k += 4) {
      float4 wv = *(const float4*)(wrow + k);
      ushort4 av = *(const ushort4*)(arow + k);
      part += (av.x & 0x8000) ? -wv.x : wv.x;
      part += (av.y & 0x8000) ? -wv.y : wv.y;
      part += (av.z & 0x8000) ? -wv.z : wv.z;
      part += (av.w & 0x8000) ? -wv.w : wv.w;
    }
    float c = __shfl(part, 0, 8);
#pragma unroll
    for (int q = 1; q < 8; ++q) c += __shfl(part, q, 8);
    if (lane == 0) {
      Anext[(size_t)b * NU + j] =
          (c >= 0.0f) ? (unsigned short)0x3F80u : (unsigned short)0xBF80u;
      if (writeOut) outF[(size_t)b * NU + j] = (c >= 0.0f) ? 1.0f : -1.0f;
    }
  }
}

// Tripwire: if the suspect list ever overflows, poison the output signature.
__global__ void assemble_kernel(float* __restrict__ out,
                                const int* __restrict__ flags) {
  if (threadIdx.x != 0 || blockIdx.x != 0) return;
  if (flags[1]) out[0] = 7777.0f;
}

extern "C" void kernel_launch(void* const* d_in, const int* in_sizes, int n_in,
                              void* d_out, int out_size, void* d_ws, size_t ws_size,
                              hipStream_t stream) {
  const float* P = (const float*)d_in[0];
  const float* W = (const float*)d_in[1];
  float* out = (float*)d_out;

  if (n_in < 2 || in_sizes[0] != NB * NU || in_sizes[1] != NU * NU ||
      out_size != NB * NU) {
    fill_kernel<<<4096, 256, 0, stream>>>(out, 9.0f);
    return;
  }
  if (ws_size < (size_t)REQ_WS) {
    fill_kernel<<<4096, 256, 0, stream>>>(out, 3.0f);
    return;
  }

  char* w = (char*)d_ws;
  unsigned short* Bt = (unsigned short*)(w + OFF_BT);
  unsigned short* A0 = (unsigned short*)(w + OFF_A0);
  unsigned short* A1 = (unsigned short*)(w + OFF_A1);
  int* suspects = (int*)(w + OFF_SUS);
  int* counters = (int*)(w + OFF_CNT);
  int* flags = counters + 128;  // [1]=suspect overflow

  hipMemsetAsync(counters, 0, 1024, stream);
  decompose_kernel<<<16384, 256, 0, stream>>>(W, Bt);
  init_kernel<<<4096, 256, 0, stream>>>(P, A0);

  for (int t = 0; t < ITERS; ++t) {
    unsigned short* Ain = (t & 1) ? A1 : A0;
    unsigned short* Aout = (t & 1) ? A0 : A1;
    int fin = (t == ITERS - 1) ? 1 : 0;
    gemm_fused_kernel<<<256, 512, 0, stream>>>(Ain, Bt, Aout, out, fin,
                                               &counters[t], suspects);
    fixup_kernel<<<256, 256, 0, stream>>>(Ain, W, Aout, out, fin,
                                          &counters[t], suspects, &flags[1]);
  }
  assemble_kernel<<<1, 64, 0, stream>>>(out, flags);
}

// Round 3
// 13839.337 us; speedup vs baseline: 1.3556x; 1.1061x over previous
//
#include <hip/hip_runtime.h>
#include <stdint.h>

#define NU 4096
#define NB 2048
#define KK2 8192
#define ITERS 100
#define CAP 262144
#define THETA 0.05f
#define KC 512              // host fixup k-panel (verified)

// ws layout (bytes) — unchanged
#define OFF_BT   0u
#define OFF_A0   67108864u
#define OFF_A1   83886080u
#define OFF_SUS  100663296u
#define OFF_CNT  102760448u
#define REQ_WS   102761472u

// GEMM geometry: BM=256 x BN=128, 512 thr (8 waves 4Mx2N, wave-tile 64x64).
// Double-tile fusion: K-tile kt (W_hi) and kt+64 (W_lo) share the SAME A
// slice -> A fragments read from LDS once, A staged once. 64 double-tiles.
#define NDT 64
#define BBASE 65536          // byte offset of B buffers in sL

typedef float f32x4 __attribute__((ext_vector_type(4)));
typedef __bf16 bf16x8 __attribute__((ext_vector_type(8)));

__device__ __forceinline__ unsigned short f2bf(float x) {
  unsigned u = __float_as_uint(x);
  u += 0x7FFFu + ((u >> 16) & 1u);
  return (unsigned short)(u >> 16);
}
__device__ __forceinline__ float bf2f(unsigned short h) {
  return __uint_as_float(((unsigned)h) << 16);
}

__device__ __forceinline__ void gl16(const unsigned short* g, char* l) {
  __builtin_amdgcn_global_load_lds(
      (const __attribute__((address_space(1))) unsigned int*)g,
      (__attribute__((address_space(3))) unsigned int*)l, 16, 0, 0);
}

__global__ void fill_kernel(float* __restrict__ out, float v) {
  int t = blockIdx.x * blockDim.x + threadIdx.x;
  int base = t << 3;
  float4 a = make_float4(v, v, v, v);
  *(float4*)(out + base) = a;
  *(float4*)(out + base + 4) = a;
}

__global__ void decompose_kernel(const float* __restrict__ W,
                                 unsigned short* __restrict__ Bt) {
  int t = blockIdx.x * blockDim.x + threadIdx.x;
  int base = t << 2;
  int j = base >> 12;
  int k = base & 4095;
  float4 w = *(const float4*)(W + (size_t)j * NU + k);
  unsigned short h0 = f2bf(w.x), h1 = f2bf(w.y), h2 = f2bf(w.z), h3 = f2bf(w.w);
  ushort4 hi = make_ushort4(h0, h1, h2, h3);
  ushort4 lo = make_ushort4(f2bf(w.x - bf2f(h0)), f2bf(w.y - bf2f(h1)),
                            f2bf(w.z - bf2f(h2)), f2bf(w.w - bf2f(h3)));
  *(ushort4*)(Bt + (size_t)j * KK2 + k) = hi;
  *(ushort4*)(Bt + (size_t)j * KK2 + NU + k) = lo;
}

// Initial state: P (fp32 +-1, exact) -> A0 bf16 +-1.
__global__ void init_kernel(const float* __restrict__ P,
                            unsigned short* __restrict__ A0) {
  int t = blockIdx.x * blockDim.x + threadIdx.x;
  int base = t << 3;
  float4 a = *(const float4*)(P + base);
  float4 b = *(const float4*)(P + base + 4);
  float hv[8] = {a.x, a.y, a.z, a.w, b.x, b.y, b.z, b.w};
  uint4 pk;
  unsigned short s[8];
#pragma unroll
  for (int i = 0; i < 8; ++i)
    s[i] = (hv[i] >= 0.0f) ? (unsigned short)0x3F80u : (unsigned short)0xBF80u;
  pk.x = (unsigned)s[0] | ((unsigned)s[1] << 16);
  pk.y = (unsigned)s[2] | ((unsigned)s[3] << 16);
  pk.z = (unsigned)s[4] | ((unsigned)s[5] << 16);
  pk.w = (unsigned)s[6] | ((unsigned)s[7] << 16);
  *(uint4*)(A0 + base) = pk;
}

// ---- schedule primitives (m201 template port) ----
#define BAR() do { __builtin_amdgcn_sched_barrier(0);          \
                   __builtin_amdgcn_s_barrier();               \
                   __builtin_amdgcn_sched_barrier(0); } while (0)
#define LGK0() do { asm volatile("s_waitcnt lgkmcnt(0)" ::: "memory"); \
                    __builtin_amdgcn_sched_barrier(0); } while (0)
#define VM0() do { asm volatile("s_waitcnt vmcnt(0)" ::: "memory");    \
                   __builtin_amdgcn_sched_barrier(0); } while (0)
#define MM(AF, BF) do { __builtin_amdgcn_s_setprio(1);                       \
  _Pragma("unroll") for (int i_ = 0; i_ < 4; ++i_)                           \
  _Pragma("unroll") for (int j_ = 0; j_ < 4; ++j_)                           \
    acc[i_][j_] = __builtin_amdgcn_mfma_f32_16x16x32_bf16(                   \
        AF[i_], BF[j_], acc[i_][j_], 0, 0, 0);                               \
  __builtin_amdgcn_s_setprio(0); } while (0)
#define RD4(DST, BASE, TT) _Pragma("unroll")                                  \
  for (int q_ = 0; q_ < 4; ++q_)                                              \
    DST[q_] = *(const bf16x8*)((BASE) + q_ * 2048 + (TT));

// 4-phase double-tile GEMM. Per phase: {ds_reads || global_load_lds prefetch}
// -> barrier -> lgkmcnt(0) -> setprio(1) 16xMFMA setprio(0) -> barrier.
// 2-deep LDS buffering (A[2]:32KB each @0/32768, B[2]:32KB @65536/98304 =
// 128 KiB exact). STAGE(k+1) spread over phases 0-2; single vmcnt(0) at
// phase-3 end (loads ~3 phases old -> drain free). Swizzle: LDS linear dest,
// inverse-swizzled global source, swizzled ds_read — bit-identical formulas
// to the round-1 kernel that measured SQ_LDS_BANK_CONFLICT == 0.
// Ledger: iter k reads buf k&1, stages buf (k+1)&1; last reads of a buffer
// retire via each wave's lgkmcnt(0) before the end-of-iter barrier; staging
// visibility via own-wave vmcnt(0) + that barrier. No overlap window.
// MFMA core & C/D mapping unchanged (certified m89/m91).
__global__ void __launch_bounds__(512, 1)
gemm_fused_kernel(const unsigned short* __restrict__ A,
                  const unsigned short* __restrict__ Bt,
                  unsigned short* __restrict__ Anext,
                  float* __restrict__ outF, int writeOut,
                  int* __restrict__ counter,
                  int* __restrict__ suspects) {
  __shared__ __align__(16) unsigned short sL[65536];   // 131072 B
  const int tid = threadIdx.x;
  const int wave = tid >> 6, lane = tid & 63;
  const int lm = lane & 15, lk = lane >> 4;
  const int wm = wave >> 1, wn = wave & 1;             // 4M x 2N wave grid
  const int nt = blockIdx.x & 31, mt = blockIdx.x >> 5;
  const int mBase = mt << 8, nBase = nt << 7;

  // ---- staging lane constants (chunk = 128 rows x 64 cols = 16 KB) ----
  const int rl0 = (wave << 4) + (lane >> 3);
  const int swz = (((lane & 7) ^ ((lane >> 3) & 7)) << 3);  // elems
  const unsigned short* pA00 = A + (size_t)(mBase + rl0) * NU + swz;
  const unsigned short* pA01 = A + (size_t)(mBase + rl0 + 8) * NU + swz;
  const unsigned short* pA10 = A + (size_t)(mBase + 128 + rl0) * NU + swz;
  const unsigned short* pA11 = A + (size_t)(mBase + 128 + rl0 + 8) * NU + swz;
  const unsigned short* pB0 = Bt + (size_t)(nBase + rl0) * KK2 + swz;
  const unsigned short* pB1 = Bt + (size_t)(nBase + rl0 + 8) * KK2 + swz;
  const int ldsW = wave << 11;                         // wave * 2048 B
  char* sBase = (char*)sL;

  // ---- fragment-read lane constants ----
  const int t0 = ((lk ^ (lm & 7)) << 4);
  const int t1 = t0 ^ 64;
  const int aB = (((wm << 6) + lm) << 7);              // A row*128 B
  const int bB = (((wn << 6) + lm) << 7);              // B row*128 B (rel.)

  f32x4 acc[4][4] = {};

  // prologue: stage double-tile 0 into buffer 0
  {
    char* nA = sBase;
    char* nB = sBase + BBASE;
    gl16(pA00, nA + ldsW);          gl16(pA01, nA + ldsW + 1024);
    gl16(pA10, nA + 16384 + ldsW);  gl16(pA11, nA + 16384 + ldsW + 1024);
    gl16(pB0, nB + ldsW);           gl16(pB1, nB + ldsW + 1024);
    gl16(pB0 + 4096, nB + 16384 + ldsW);
    gl16(pB1 + 4096, nB + 16384 + ldsW + 1024);
  }
  VM0();
  BAR();

  for (int k = 0; k < NDT; ++k) {
    const int cur = k & 1, nx = cur ^ 1;
    const char* cA = sBase + (cur << 15);
    const char* cB = sBase + BBASE + (cur << 15);
    char* nA = sBase + (nx << 15);
    char* nB = sBase + BBASE + (nx << 15);
    const bool pf = (k + 1 < NDT);                     // block-uniform
    const int kN = (k + 1) << 6;                       // next tile K col
    bf16x8 af0[4], af1[4], bf[4];

    // ---- phase 0: af0 + B_hi(kks0); stage A(k+1); MFMA hi-kks0
    RD4(af0, cA + aB, t0);
    RD4(bf, cB + bB, t0);
    if (pf) {
      gl16(pA00 + kN, nA + ldsW);         gl16(pA01 + kN, nA + ldsW + 1024);
      gl16(pA10 + kN, nA + 16384 + ldsW); gl16(pA11 + kN, nA + 16384 + ldsW + 1024);
    }
    BAR(); LGK0();
    MM(af0, bf);
    BAR();

    // ---- phase 1: af1 + B_hi(kks1); stage B_hi(k+1); MFMA hi-kks1
    RD4(af1, cA + aB, t1);
    RD4(bf, cB + bB, t1);
    if (pf) { gl16(pB0 + kN, nB + ldsW); gl16(pB1 + kN, nB + ldsW + 1024); }
    BAR(); LGK0();
    MM(af1, bf);
    BAR();

    // ---- phase 2: B_lo(kks0); stage B_lo(k+1); MFMA lo-kks0 (reuses af0)
    RD4(bf, cB + 16384 + bB, t0);
    if (pf) {
      gl16(pB0 + kN + 4096, nB + 16384 + ldsW);
      gl16(pB1 + kN + 4096, nB + 16384 + ldsW + 1024);
    }
    BAR(); LGK0();
    MM(af0, bf);
    BAR();

    // ---- phase 3: B_lo(kks1); MFMA lo-kks1 (reuses af1); drain staging
    RD4(bf, cB + 16384 + bB, t1);
    BAR(); LGK0();
    MM(af1, bf);
    VM0();                // retire tile k+1's 8 loads (issued ~3 phases ago)
    BAR();
  }

  // Fused sign epilogue. C/D layout (m89/m91): col=lane&15, row=(lane>>4)*4+reg
#pragma unroll
  for (int i = 0; i < 4; ++i)
#pragma unroll
    for (int j = 0; j < 4; ++j)
#pragma unroll
      for (int r = 0; r < 4; ++r) {
        const int row = mBase + (wm << 6) + i * 16 + (lk << 2) + r;
        const int col = nBase + (wn << 6) + j * 16 + lm;
        const float h = acc[i][j][r];
        Anext[(size_t)row * NU + col] =
            (h >= 0.0f) ? (unsigned short)0x3F80u : (unsigned short)0xBF80u;
        if (fabsf(h) < THETA) {
          int idx = atomicAdd(counter, 1);
          if (idx < CAP) suspects[idx] = (row << 12) | col;
        }
        if (writeOut)
          outF[(size_t)row * NU + col] = (h >= 0.0f) ? 1.0f : -1.0f;
      }
}

// Suspects, 8 lanes per suspect (one per KC=512 panel). Same sequential fp32
// chain as the round-8-verified version; bitwise-identical sign decision.
__global__ void fixup_kernel(const unsigned short* __restrict__ Acur,
                             const float* __restrict__ W,
                             unsigned short* __restrict__ Anext,
                             float* __restrict__ outF, int writeOut,
                             const int* __restrict__ counter,
                             const int* __restrict__ suspects,
                             int* __restrict__ flagOv) {
  int n = *counter;
  if (blockIdx.x == 0 && threadIdx.x == 0 && n > CAP) atomicAdd(flagOv, 1);
  n = n < CAP ? n : CAP;
  const int lane = threadIdx.x & 7;                       // panel index
  const int gid = (blockIdx.x * blockDim.x + threadIdx.x) >> 3;
  const int ngrp = (gridDim.x * blockDim.x) >> 3;
  for (int i = gid; i < n; i += ngrp) {
    int idx = suspects[i];
    int b = idx >> 12, j = idx & 4095;
    const float* wrow = W + (size_t)j * NU + lane * KC;
    const unsigned short* arow = Acur + (size_t)b * NU + lane * KC;
    float part = 0.0f;
    for (int k = 0; k < KC; k += 4) {
      float4 wv = *(const float4*)(wrow + k);
      ushort4 av = *(const ushort4*)(arow + k);
      part += (av.x & 0x8000) ? -wv.x : wv.x;
      part += (av.y & 0x8000) ? -wv.y : wv.y;
      part += (av.z & 0x8000) ? -wv.z : wv.z;
      part += (av.w & 0x8000) ? -wv.w : wv.w;
    }
    float c = __shfl(part, 0, 8);
#pragma unroll
    for (int q = 1; q < 8; ++q) c += __shfl(part, q, 8);
    if (lane == 0) {
      Anext[(size_t)b * NU + j] =
          (c >= 0.0f) ? (unsigned short)0x3F80u : (unsigned short)0xBF80u;
      if (writeOut) outF[(size_t)b * NU + j] = (c >= 0.0f) ? 1.0f : -1.0f;
    }
  }
}

// Tripwire: if the suspect list ever overflows, poison the output signature.
__global__ void assemble_kernel(float* __restrict__ out,
                                const int* __restrict__ flags) {
  if (threadIdx.x != 0 || blockIdx.x != 0) return;
  if (flags[1]) out[0] = 7777.0f;
}

extern "C" void kernel_launch(void* const* d_in, const int* in_sizes, int n_in,
                              void* d_out, int out_size, void* d_ws, size_t ws_size,
                              hipStream_t stream) {
  const float* P = (const float*)d_in[0];
  const float* W = (const float*)d_in[1];
  float* out = (float*)d_out;

  if (n_in < 2 || in_sizes[0] != NB * NU || in_sizes[1] != NU * NU ||
      out_size != NB * NU) {
    fill_kernel<<<4096, 256, 0, stream>>>(out, 9.0f);
    return;
  }
  if (ws_size < (size_t)REQ_WS) {
    fill_kernel<<<4096, 256, 0, stream>>>(out, 3.0f);
    return;
  }

  char* w = (char*)d_ws;
  unsigned short* Bt = (unsigned short*)(w + OFF_BT);
  unsigned short* A0 = (unsigned short*)(w + OFF_A0);
  unsigned short* A1 = (unsigned short*)(w + OFF_A1);
  int* suspects = (int*)(w + OFF_SUS);
  int* counters = (int*)(w + OFF_CNT);
  int* flags = counters + 128;  // [1]=suspect overflow

  hipMemsetAsync(counters, 0, 1024, stream);
  decompose_kernel<<<16384, 256, 0, stream>>>(W, Bt);
  init_kernel<<<4096, 256, 0, stream>>>(P, A0);

  for (int t = 0; t < ITERS; ++t) {
    unsigned short* Ain = (t & 1) ? A1 : A0;
    unsigned short* Aout = (t & 1) ? A0 : A1;
    int fin = (t == ITERS - 1) ? 1 : 0;
    gemm_fused_kernel<<<256, 512, 0, stream>>>(Ain, Bt, Aout, out, fin,
                                               &counters[t], suspects);
    fixup_kernel<<<256, 256, 0, stream>>>(Ain, W, Aout, out, fin,
                                          &counters[t], suspects, &flags[1]);
  }
  assemble_kernel<<<1, 64, 0, stream>>>(out, flags);
}

// Round 4
// 13113.048 us; speedup vs baseline: 1.4307x; 1.0554x over previous
//
#include <hip/hip_runtime.h>
#include <stdint.h>

#define NU 4096
#define NB 2048
#define KK2 8192
#define ITERS 100
#define CAP 262144
#define THETA 0.05f
#define KC 512              // host fixup k-panel (verified)

// ws layout (bytes) — unchanged
#define OFF_BT   0u
#define OFF_A0   67108864u
#define OFF_A1   83886080u
#define OFF_SUS  100663296u
#define OFF_CNT  102760448u
#define REQ_WS   102761472u

// GEMM geometry: BM=256 x BN=128, 512 thr (8 waves 4Mx2N, wave-tile 64x64).
// Double-tile fusion: K-tile kt (W_hi) and kt+64 (W_lo) share the SAME A
// slice -> A fragments read from LDS once, A staged once. 64 double-tiles.
#define NDT 64
#define BBASE 65536          // byte offset of B buffers in sL

typedef float f32x4 __attribute__((ext_vector_type(4)));
typedef __bf16 bf16x8 __attribute__((ext_vector_type(8)));

__device__ __forceinline__ unsigned short f2bf(float x) {
  unsigned u = __float_as_uint(x);
  u += 0x7FFFu + ((u >> 16) & 1u);
  return (unsigned short)(u >> 16);
}
__device__ __forceinline__ float bf2f(unsigned short h) {
  return __uint_as_float(((unsigned)h) << 16);
}

__device__ __forceinline__ void gl16(const unsigned short* g, char* l) {
  __builtin_amdgcn_global_load_lds(
      (const __attribute__((address_space(1))) unsigned int*)g,
      (__attribute__((address_space(3))) unsigned int*)l, 16, 0, 0);
}

__global__ void fill_kernel(float* __restrict__ out, float v) {
  int t = blockIdx.x * blockDim.x + threadIdx.x;
  int base = t << 3;
  float4 a = make_float4(v, v, v, v);
  *(float4*)(out + base) = a;
  *(float4*)(out + base + 4) = a;
}

__global__ void decompose_kernel(const float* __restrict__ W,
                                 unsigned short* __restrict__ Bt) {
  int t = blockIdx.x * blockDim.x + threadIdx.x;
  int base = t << 2;
  int j = base >> 12;
  int k = base & 4095;
  float4 w = *(const float4*)(W + (size_t)j * NU + k);
  unsigned short h0 = f2bf(w.x), h1 = f2bf(w.y), h2 = f2bf(w.z), h3 = f2bf(w.w);
  ushort4 hi = make_ushort4(h0, h1, h2, h3);
  ushort4 lo = make_ushort4(f2bf(w.x - bf2f(h0)), f2bf(w.y - bf2f(h1)),
                            f2bf(w.z - bf2f(h2)), f2bf(w.w - bf2f(h3)));
  *(ushort4*)(Bt + (size_t)j * KK2 + k) = hi;
  *(ushort4*)(Bt + (size_t)j * KK2 + NU + k) = lo;
}

// Initial state: P (fp32 +-1, exact) -> A0 bf16 +-1.
__global__ void init_kernel(const float* __restrict__ P,
                            unsigned short* __restrict__ A0) {
  int t = blockIdx.x * blockDim.x + threadIdx.x;
  int base = t << 3;
  float4 a = *(const float4*)(P + base);
  float4 b = *(const float4*)(P + base + 4);
  float hv[8] = {a.x, a.y, a.z, a.w, b.x, b.y, b.z, b.w};
  uint4 pk;
  unsigned short s[8];
#pragma unroll
  for (int i = 0; i < 8; ++i)
    s[i] = (hv[i] >= 0.0f) ? (unsigned short)0x3F80u : (unsigned short)0xBF80u;
  pk.x = (unsigned)s[0] | ((unsigned)s[1] << 16);
  pk.y = (unsigned)s[2] | ((unsigned)s[3] << 16);
  pk.z = (unsigned)s[4] | ((unsigned)s[5] << 16);
  pk.w = (unsigned)s[6] | ((unsigned)s[7] << 16);
  *(uint4*)(A0 + base) = pk;
}

// ---- schedule primitives ----
#define SCB() __builtin_amdgcn_sched_barrier(0)
#define BAR() do { __builtin_amdgcn_sched_barrier(0);          \
                   __builtin_amdgcn_s_barrier();               \
                   __builtin_amdgcn_sched_barrier(0); } while (0)
#define VM0() do { asm volatile("s_waitcnt vmcnt(0)" ::: "memory");    \
                   __builtin_amdgcn_sched_barrier(0); } while (0)
#define MM(AF, BF) do { __builtin_amdgcn_s_setprio(1);                       \
  _Pragma("unroll") for (int i_ = 0; i_ < 4; ++i_)                           \
  _Pragma("unroll") for (int j_ = 0; j_ < 4; ++j_)                           \
    acc[i_][j_] = __builtin_amdgcn_mfma_f32_16x16x32_bf16(                   \
        AF[i_], BF[j_], acc[i_][j_], 0, 0, 0);                               \
  __builtin_amdgcn_s_setprio(0); } while (0)
#define RD4(DST, BASE, TT) _Pragma("unroll")                                  \
  for (int q_ = 0; q_ < 4; ++q_)                                              \
    DST[q_] = *(const bf16x8*)((BASE) + q_ * 2048 + (TT));

// Fragment-pipelined double-tile GEMM, ONE barrier per double-tile.
// Clusters: C0=(af0,B_hi,t0) C1=(af1,B_hi,t1) C2=(af0,B_lo,t0) C3=(af1,B_lo,t1).
// ds_reads for cluster p+1 issue BEFORE MFMA cluster p (order pinned by
// sched_barrier); waits are COMPILER-inserted counted lgkmcnt (plain loads;
// max 16 outstanding -> worst wait lgkmcnt(15), encodable). LDS read pipe
// thus runs UNDER the MFMA clusters instead of serialized by barriers.
// Ledger: per wave, lgkm outstanding <= 16 (R0+R1 at cluster-0 entry);
// vmcnt outstanding <= 8 (one tile's staging). Boundary: vmcnt(0)+s_barrier
// — every wave's cur-reads retired (compiler lgkm waits precede last MFMA),
// nx fully staged & visible; only then are next-tile fragments issued and
// (next iter, post-barrier) gl16 writes to old cur allowed. No overlap window.
// Swizzle formulas bit-identical to round-1 kernel (measured 0 conflicts).
// MFMA core & C/D mapping unchanged (certified m89/m91).
__global__ void __launch_bounds__(512, 1)
gemm_fused_kernel(const unsigned short* __restrict__ A,
                  const unsigned short* __restrict__ Bt,
                  unsigned short* __restrict__ Anext,
                  float* __restrict__ outF, int writeOut,
                  int* __restrict__ counter,
                  int* __restrict__ suspects) {
  __shared__ __align__(16) unsigned short sL[65536];   // 131072 B
  const int tid = threadIdx.x;
  const int wave = tid >> 6, lane = tid & 63;
  const int lm = lane & 15, lk = lane >> 4;
  const int wm = wave >> 1, wn = wave & 1;             // 4M x 2N wave grid
  const int nt = blockIdx.x & 31, mt = blockIdx.x >> 5;
  const int mBase = mt << 8, nBase = nt << 7;

  // ---- staging lane constants (chunk = 128 rows x 64 cols = 16 KB) ----
  const int rl0 = (wave << 4) + (lane >> 3);
  const int swz = (((lane & 7) ^ ((lane >> 3) & 7)) << 3);  // elems
  const unsigned short* pA00 = A + (size_t)(mBase + rl0) * NU + swz;
  const unsigned short* pA01 = A + (size_t)(mBase + rl0 + 8) * NU + swz;
  const unsigned short* pA10 = A + (size_t)(mBase + 128 + rl0) * NU + swz;
  const unsigned short* pA11 = A + (size_t)(mBase + 128 + rl0 + 8) * NU + swz;
  const unsigned short* pB0 = Bt + (size_t)(nBase + rl0) * KK2 + swz;
  const unsigned short* pB1 = Bt + (size_t)(nBase + rl0 + 8) * KK2 + swz;
  const int ldsW = wave << 11;                         // wave * 2048 B
  char* sBase = (char*)sL;

  // ---- fragment-read lane constants ----
  const int t0 = ((lk ^ (lm & 7)) << 4);
  const int t1 = t0 ^ 64;
  const int aB = (((wm << 6) + lm) << 7);              // A row*128 B
  const int bB = (((wn << 6) + lm) << 7);              // B row*128 B (rel.)

  f32x4 acc[4][4] = {};
  bf16x8 af0[4], af1[4], bf0[4], bf1[4], bf2[4], bf3[4];

  // prologue: stage double-tile 0 into buffer 0
  {
    char* nA = sBase;
    char* nB = sBase + BBASE;
    gl16(pA00, nA + ldsW);          gl16(pA01, nA + ldsW + 1024);
    gl16(pA10, nA + 16384 + ldsW);  gl16(pA11, nA + 16384 + ldsW + 1024);
    gl16(pB0, nB + ldsW);           gl16(pB1, nB + ldsW + 1024);
    gl16(pB0 + 4096, nB + 16384 + ldsW);
    gl16(pB1 + 4096, nB + 16384 + ldsW + 1024);
  }
  VM0();
  BAR();
  // issue R0 (af0,bf0) and R1 (af1,bf1) from buffer 0  [16 reads in flight]
  RD4(af0, sBase + aB, t0);
  RD4(bf0, sBase + BBASE + bB, t0);
  RD4(af1, sBase + aB, t1);
  RD4(bf1, sBase + BBASE + bB, t1);

  for (int k = 0; k < NDT; ++k) {
    const int cur = k & 1, nx = cur ^ 1;
    const char* cB = sBase + BBASE + (cur << 15);
    char* nA = sBase + (nx << 15);
    char* nB = sBase + BBASE + (nx << 15);
    const bool pf = (k + 1 < NDT);                     // block-uniform
    const int kN = (k + 1) << 6;                       // next tile K col
    SCB();
    // ---- cluster 0: C += af0 x B_hi(t0)   [compiler waits R0: lgkmcnt(8)]
    MM(af0, bf0);
    SCB();
    // issue R2 (B_lo t0) + stage A(k+1); runs under cluster 1
    RD4(bf2, cB + 16384 + bB, t0);
    if (pf) {
      gl16(pA00 + kN, nA + ldsW);         gl16(pA01 + kN, nA + ldsW + 1024);
      gl16(pA10 + kN, nA + 16384 + ldsW); gl16(pA11 + kN, nA + 16384 + ldsW + 1024);
    }
    SCB();
    // ---- cluster 1: C += af1 x B_hi(t1)   [waits R1]
    MM(af1, bf1);
    SCB();
    // issue R3 (B_lo t1) + stage B_hi/B_lo(k+1); runs under cluster 2
    RD4(bf3, cB + 16384 + bB, t1);
    if (pf) {
      gl16(pB0 + kN, nB + ldsW);          gl16(pB1 + kN, nB + ldsW + 1024);
      gl16(pB0 + kN + 4096, nB + 16384 + ldsW);
      gl16(pB1 + kN + 4096, nB + 16384 + ldsW + 1024);
    }
    SCB();
    // ---- cluster 2: C += af0 x B_lo(t0)   [waits R2]
    MM(af0, bf2);
    SCB();
    // ---- cluster 3: C += af1 x B_lo(t1)   [waits R3]
    MM(af1, bf3);
    SCB();
    if (pf) {
      VM0();             // own staging of tile k+1 landed (oldest ~3 clusters)
      BAR();             // all waves: cur-reads retired, nx visible
      // issue next tile's R0,R1 from nx  [16 reads in flight at loop head]
      RD4(af0, nA + aB, t0);
      RD4(bf0, nB + bB, t0);
      RD4(af1, nA + aB, t1);
      RD4(bf1, nB + bB, t1);
    }
  }

  // Fused sign epilogue. C/D layout (m89/m91): col=lane&15, row=(lane>>4)*4+reg
#pragma unroll
  for (int i = 0; i < 4; ++i)
#pragma unroll
    for (int j = 0; j < 4; ++j)
#pragma unroll
      for (int r = 0; r < 4; ++r) {
        const int row = mBase + (wm << 6) + i * 16 + (lk << 2) + r;
        const int col = nBase + (wn << 6) + j * 16 + lm;
        const float h = acc[i][j][r];
        Anext[(size_t)row * NU + col] =
            (h >= 0.0f) ? (unsigned short)0x3F80u : (unsigned short)0xBF80u;
        if (fabsf(h) < THETA) {
          int idx = atomicAdd(counter, 1);
          if (idx < CAP) suspects[idx] = (row << 12) | col;
        }
        if (writeOut)
          outF[(size_t)row * NU + col] = (h >= 0.0f) ? 1.0f : -1.0f;
      }
}

// Suspects, 8 lanes per suspect (one per KC=512 panel). Same sequential fp32
// chain as the round-8-verified version; bitwise-identical sign decision.
__global__ void fixup_kernel(const unsigned short* __restrict__ Acur,
                             const float* __restrict__ W,
                             unsigned short* __restrict__ Anext,
                             float* __restrict__ outF, int writeOut,
                             const int* __restrict__ counter,
                             const int* __restrict__ suspects,
                             int* __restrict__ flagOv) {
  int n = *counter;
  if (blockIdx.x == 0 && threadIdx.x == 0 && n > CAP) atomicAdd(flagOv, 1);
  n = n < CAP ? n : CAP;
  const int lane = threadIdx.x & 7;                       // panel index
  const int gid = (blockIdx.x * blockDim.x + threadIdx.x) >> 3;
  const int ngrp = (gridDim.x * blockDim.x) >> 3;
  for (int i = gid; i < n; i += ngrp) {
    int idx = suspects[i];
    int b = idx >> 12, j = idx & 4095;
    const float* wrow = W + (size_t)j * NU + lane * KC;
    const unsigned short* arow = Acur + (size_t)b * NU + lane * KC;
    float part = 0.0f;
    for (int k = 0; k < KC; k += 4) {
      float4 wv = *(const float4*)(wrow + k);
      ushort4 av = *(const ushort4*)(arow + k);
      part += (av.x & 0x8000) ? -wv.x : wv.x;
      part += (av.y & 0x8000) ? -wv.y : wv.y;
      part += (av.z & 0x8000) ? -wv.z : wv.z;
      part += (av.w & 0x8000) ? -wv.w : wv.w;
    }
    float c = __shfl(part, 0, 8);
#pragma unroll
    for (int q = 1; q < 8; ++q) c += __shfl(part, q, 8);
    if (lane == 0) {
      Anext[(size_t)b * NU + j] =
          (c >= 0.0f) ? (unsigned short)0x3F80u : (unsigned short)0xBF80u;
      if (writeOut) outF[(size_t)b * NU + j] = (c >= 0.0f) ? 1.0f : -1.0f;
    }
  }
}

// Tripwire: if the suspect list ever overflows, poison the output signature.
__global__ void assemble_kernel(float* __restrict__ out,
                                const int* __restrict__ flags) {
  if (threadIdx.x != 0 || blockIdx.x != 0) return;
  if (flags[1]) out[0] = 7777.0f;
}

extern "C" void kernel_launch(void* const* d_in, const int* in_sizes, int n_in,
                              void* d_out, int out_size, void* d_ws, size_t ws_size,
                              hipStream_t stream) {
  const float* P = (const float*)d_in[0];
  const float* W = (const float*)d_in[1];
  float* out = (float*)d_out;

  if (n_in < 2 || in_sizes[0] != NB * NU || in_sizes[1] != NU * NU ||
      out_size != NB * NU) {
    fill_kernel<<<4096, 256, 0, stream>>>(out, 9.0f);
    return;
  }
  if (ws_size < (size_t)REQ_WS) {
    fill_kernel<<<4096, 256, 0, stream>>>(out, 3.0f);
    return;
  }

  char* w = (char*)d_ws;
  unsigned short* Bt = (unsigned short*)(w + OFF_BT);
  unsigned short* A0 = (unsigned short*)(w + OFF_A0);
  unsigned short* A1 = (unsigned short*)(w + OFF_A1);
  int* suspects = (int*)(w + OFF_SUS);
  int* counters = (int*)(w + OFF_CNT);
  int* flags = counters + 128;  // [1]=suspect overflow

  hipMemsetAsync(counters, 0, 1024, stream);
  decompose_kernel<<<16384, 256, 0, stream>>>(W, Bt);
  init_kernel<<<4096, 256, 0, stream>>>(P, A0);

  for (int t = 0; t < ITERS; ++t) {
    unsigned short* Ain = (t & 1) ? A1 : A0;
    unsigned short* Aout = (t & 1) ? A0 : A1;
    int fin = (t == ITERS - 1) ? 1 : 0;
    gemm_fused_kernel<<<256, 512, 0, stream>>>(Ain, Bt, Aout, out, fin,
                                               &counters[t], suspects);
    fixup_kernel<<<256, 256, 0, stream>>>(Ain, W, Aout, out, fin,
                                          &counters[t], suspects, &flags[1]);
  }
  assemble_kernel<<<1, 64, 0, stream>>>(out, flags);
}